// Round 1
// baseline (1664.646 us; speedup 1.0000x reference)
//
#include <hip/hip_runtime.h>
#include <stdint.h>

// MoE top-2 routed SwiGLU. B=2,S=1024 -> T=2048 tokens, D=2048, F=8192, E=4, K=2.
// Pipeline: router -> gather(bf16) -> per-expert {transpose-convert W, gemm12(fused gate/up+silu), gemm3(scatter-add)}.
// GEMMs: m97 structure — 128x128 tile, BK=64, global_load_lds width=16, XOR-swizzled LDS, mfma_f32_16x16x32_bf16.

#define T_TOK 2048
#define DM    2048
#define FF    8192

typedef unsigned short u16;
typedef short short8 __attribute__((ext_vector_type(8)));
typedef float f32x4  __attribute__((ext_vector_type(4)));

#define GLL16(g, l) __builtin_amdgcn_global_load_lds( \
    (const __attribute__((address_space(1))) void*)(g), \
    (__attribute__((address_space(3))) void*)(l), 16, 0, 0)

__device__ __forceinline__ u16 f2bf(float f) {
  uint32_t x = __float_as_uint(f);
  x += 0x7fffu + ((x >> 16) & 1u);
  return (u16)(x >> 16);
}

// ---------------- router: probs + top2 + slot assignment ----------------
__global__ __launch_bounds__(256) void router_kernel(
    const float* __restrict__ x, const float* __restrict__ Wr,
    int* __restrict__ counts, int* __restrict__ tok, float* __restrict__ gate)
{
  int t = blockIdx.x * 4 + (threadIdx.x >> 6);   // one wave per token
  int l = threadIdx.x & 63;
  const float* xr = x + (size_t)t * DM;
  const float4* wr4 = (const float4*)Wr;         // Wr row d = 4 consecutive floats
  float a0 = 0.f, a1 = 0.f, a2 = 0.f, a3 = 0.f;
  for (int d = l; d < DM; d += 64) {
    float xv = xr[d];
    float4 w = wr4[d];
    a0 += xv * w.x; a1 += xv * w.y; a2 += xv * w.z; a3 += xv * w.w;
  }
  #pragma unroll
  for (int off = 32; off > 0; off >>= 1) {
    a0 += __shfl_down(a0, off);
    a1 += __shfl_down(a1, off);
    a2 += __shfl_down(a2, off);
    a3 += __shfl_down(a3, off);
  }
  if (l == 0) {
    float lg[4] = {a0, a1, a2, a3};
    float m = fmaxf(fmaxf(lg[0], lg[1]), fmaxf(lg[2], lg[3]));
    float p[4], s = 0.f;
    #pragma unroll
    for (int e = 0; e < 4; ++e) { p[e] = __expf(lg[e] - m); s += p[e]; }
    #pragma unroll
    for (int e = 0; e < 4; ++e) p[e] /= s;
    int i0 = 0;
    #pragma unroll
    for (int e = 1; e < 4; ++e) if (p[e] > p[i0]) i0 = e;      // ties -> lower idx, matches lax.top_k
    int i1 = (i0 == 0) ? 1 : 0;
    #pragma unroll
    for (int e = 0; e < 4; ++e) if (e != i0 && p[e] > p[i1]) i1 = e;
    int s0 = atomicAdd(&counts[i0], 1);
    tok[i0 * T_TOK + s0] = t; gate[i0 * T_TOK + s0] = p[i0];
    int s1 = atomicAdd(&counts[i1], 1);
    tok[i1 * T_TOK + s1] = t; gate[i1 * T_TOK + s1] = p[i1];
  }
}

// ---------------- gather token rows -> per-expert contiguous bf16 A ----------------
__global__ __launch_bounds__(256) void gather_kernel(
    const float* __restrict__ x, const int* __restrict__ counts,
    const int* __restrict__ tok, u16* __restrict__ Xe)
{
  int e = blockIdx.x >> 11;
  int slot = blockIdx.x & (T_TOK - 1);
  if (slot >= counts[e]) return;
  int t = tok[e * T_TOK + slot];
  const float4* src = (const float4*)(x + (size_t)t * DM);
  u16* dst = Xe + ((size_t)e * T_TOK + slot) * DM;
  int i = threadIdx.x;                           // 256 thr x 8 elems = 2048
  float4 a = src[i * 2], b = src[i * 2 + 1];
  union { u16 h[8]; uint4 q; } v;
  v.h[0] = f2bf(a.x); v.h[1] = f2bf(a.y); v.h[2] = f2bf(a.z); v.h[3] = f2bf(a.w);
  v.h[4] = f2bf(b.x); v.h[5] = f2bf(b.y); v.h[6] = f2bf(b.z); v.h[7] = f2bf(b.w);
  *(uint4*)(dst + i * 8) = v.q;
}

// ---------------- transpose + fp32->bf16 convert: src[R,C] -> dst[C,R] ----------------
__global__ __launch_bounds__(256) void trans_cvt_kernel(
    const float* __restrict__ src, u16* __restrict__ dst, int R, int C)
{
  __shared__ float tile[64][65];                 // +1 pad: conflict-free transpose
  int c0 = blockIdx.x * 64, r0 = blockIdx.y * 64;
  int tid = threadIdx.x;
  int tc = tid & 63, tr = tid >> 6;
  #pragma unroll
  for (int i = 0; i < 16; ++i) {
    int row = i * 4 + tr;
    tile[row][tc] = src[(size_t)(r0 + row) * C + c0 + tc];
  }
  __syncthreads();
  int wr = tid & 15, rr = tid >> 4;
  #pragma unroll
  for (int i = 0; i < 4; ++i) {
    int row = i * 16 + rr;
    ushort4 v;
    v.x = f2bf(tile[wr * 4 + 0][row]);
    v.y = f2bf(tile[wr * 4 + 1][row]);
    v.z = f2bf(tile[wr * 4 + 2][row]);
    v.w = f2bf(tile[wr * 4 + 3][row]);
    *(ushort4*)&dst[(size_t)(c0 + row) * R + r0 + wr * 4] = v;
  }
}

// ---------------- GEMM12: H = silu(A@WgT') * (A@WuT')  [M=cnt,K=2048,N=8192] ----------------
// A [2048,2048] bf16 row-major; Bg/Bu [8192,2048] bf16 (transposed weights, k-contiguous).
__global__ __launch_bounds__(256, 2) void gemm12_kernel(
    const u16* __restrict__ A, const u16* __restrict__ Bg, const u16* __restrict__ Bu,
    u16* __restrict__ H, const int* __restrict__ cntp)
{
  const int cnt = *cntp;
  if ((int)blockIdx.y * 128 >= cnt) return;
  __shared__ __align__(16) u16 As[128 * 64];
  __shared__ __align__(16) u16 Bgs[128 * 64];
  __shared__ __align__(16) u16 Bus[128 * 64];
  const int tid = threadIdx.x, l = tid & 63, w = tid >> 6;
  const int wm = w & 1, wn = w >> 1;
  // staging: lane l covers 16B chunk (l&7) of row (l>>3) in an 8-row group; XOR swizzle on the
  // GLOBAL side (LDS dst is fixed wave-uniform base + lane*16): c_global = c_lds ^ (row&7)
  const int cg = (l & 7) ^ (l >> 3);
  const u16* ap[4]; const u16* bgp[4]; const u16* bup[4];
  const u16* la[4]; const u16* lbg[4]; const u16* lbu[4];
  #pragma unroll
  for (int j = 0; j < 4; ++j) {
    int r0 = (w * 4 + j) * 8;
    int row = r0 + (l >> 3);
    ap[j]  = A  + (size_t)(blockIdx.y * 128 + row) * DM + cg * 8;
    bgp[j] = Bg + (size_t)(blockIdx.x * 128 + row) * DM + cg * 8;
    bup[j] = Bu + (size_t)(blockIdx.x * 128 + row) * DM + cg * 8;
    la[j]  = As  + r0 * 64;
    lbg[j] = Bgs + r0 * 64;
    lbu[j] = Bus + r0 * 64;
  }
  int fm[4], fn[4];
  #pragma unroll
  for (int i = 0; i < 4; ++i) {
    fm[i] = (wm * 64 + i * 16 + (l & 15)) * 64;
    fn[i] = (wn * 64 + i * 16 + (l & 15)) * 64;
  }
  f32x4 accg[4][4] = {};
  f32x4 accu[4][4] = {};
  for (int kt = 0; kt < DM / 64; ++kt) {
    #pragma unroll
    for (int j = 0; j < 4; ++j) {
      GLL16(ap[j]  + kt * 64, la[j]);
      GLL16(bgp[j] + kt * 64, lbg[j]);
      GLL16(bup[j] + kt * 64, lbu[j]);
    }
    __syncthreads();
    #pragma unroll
    for (int kk = 0; kk < 2; ++kk) {
      const int c2 = ((kk * 4 + (l >> 4)) ^ (l & 7)) * 8;   // fragment chunk, unswizzled
      short8 af[4], bgf[4], buf_[4];
      #pragma unroll
      for (int i = 0; i < 4; ++i) af[i]   = *(const short8*)&As[fm[i] + c2];
      #pragma unroll
      for (int i = 0; i < 4; ++i) bgf[i]  = *(const short8*)&Bgs[fn[i] + c2];
      #pragma unroll
      for (int i = 0; i < 4; ++i) buf_[i] = *(const short8*)&Bus[fn[i] + c2];
      #pragma unroll
      for (int mt = 0; mt < 4; ++mt)
        #pragma unroll
        for (int nt = 0; nt < 4; ++nt) {
          accg[mt][nt] = __builtin_amdgcn_mfma_f32_16x16x32_bf16(af[mt], bgf[nt],  accg[mt][nt], 0, 0, 0);
          accu[mt][nt] = __builtin_amdgcn_mfma_f32_16x16x32_bf16(af[mt], buf_[nt], accu[mt][nt], 0, 0, 0);
        }
    }
    __syncthreads();
  }
  // epilogue: C/D layout col=lane&15, row=(lane>>4)*4+reg (m89-verified)
  const int rbase = blockIdx.y * 128 + wm * 64 + ((l >> 4) << 2);
  const int cbase = blockIdx.x * 128 + wn * 64 + (l & 15);
  #pragma unroll
  for (int mt = 0; mt < 4; ++mt) {
    #pragma unroll
    for (int i = 0; i < 4; ++i) {
      int r = rbase + mt * 16 + i;
      u16* hrow = H + (size_t)r * FF + cbase;
      #pragma unroll
      for (int nt = 0; nt < 4; ++nt) {
        float g = accg[mt][nt][i], u = accu[mt][nt][i];
        float h = (g / (1.f + __expf(-g))) * u;   // silu(g)*u
        hrow[nt * 16] = f2bf(h);
      }
    }
  }
}

// ---------------- GEMM3: out[tok[r]] += gate[r] * (H @ WdT')  [M=cnt,K=8192,N=2048] ----------------
__global__ __launch_bounds__(256, 2) void gemm3_kernel(
    const u16* __restrict__ A, const u16* __restrict__ B,
    float* __restrict__ out, const int* __restrict__ cntp,
    const int* __restrict__ tokd, const float* __restrict__ gated)
{
  const int cnt = *cntp;
  if ((int)blockIdx.y * 128 >= cnt) return;
  __shared__ __align__(16) u16 As[128 * 64];
  __shared__ __align__(16) u16 Bs[128 * 64];
  const int tid = threadIdx.x, l = tid & 63, w = tid >> 6;
  const int wm = w & 1, wn = w >> 1;
  const int cg = (l & 7) ^ (l >> 3);
  const u16* ap[4]; const u16* bp[4]; const u16* la[4]; const u16* lb[4];
  #pragma unroll
  for (int j = 0; j < 4; ++j) {
    int r0 = (w * 4 + j) * 8;
    int row = r0 + (l >> 3);
    ap[j] = A + (size_t)(blockIdx.y * 128 + row) * FF + cg * 8;
    bp[j] = B + (size_t)(blockIdx.x * 128 + row) * FF + cg * 8;
    la[j] = As + r0 * 64;
    lb[j] = Bs + r0 * 64;
  }
  int fm[4], fn[4];
  #pragma unroll
  for (int i = 0; i < 4; ++i) {
    fm[i] = (wm * 64 + i * 16 + (l & 15)) * 64;
    fn[i] = (wn * 64 + i * 16 + (l & 15)) * 64;
  }
  f32x4 acc[4][4] = {};
  for (int kt = 0; kt < FF / 64; ++kt) {
    #pragma unroll
    for (int j = 0; j < 4; ++j) {
      GLL16(ap[j] + kt * 64, la[j]);
      GLL16(bp[j] + kt * 64, lb[j]);
    }
    __syncthreads();
    #pragma unroll
    for (int kk = 0; kk < 2; ++kk) {
      const int c2 = ((kk * 4 + (l >> 4)) ^ (l & 7)) * 8;
      short8 af[4], bf[4];
      #pragma unroll
      for (int i = 0; i < 4; ++i) af[i] = *(const short8*)&As[fm[i] + c2];
      #pragma unroll
      for (int i = 0; i < 4; ++i) bf[i] = *(const short8*)&Bs[fn[i] + c2];
      #pragma unroll
      for (int mt = 0; mt < 4; ++mt)
        #pragma unroll
        for (int nt = 0; nt < 4; ++nt)
          acc[mt][nt] = __builtin_amdgcn_mfma_f32_16x16x32_bf16(af[mt], bf[nt], acc[mt][nt], 0, 0, 0);
    }
    __syncthreads();
  }
  const int rbase = blockIdx.y * 128 + wm * 64 + ((l >> 4) << 2);
  const int cbase = blockIdx.x * 128 + wn * 64 + (l & 15);
  #pragma unroll
  for (int mt = 0; mt < 4; ++mt) {
    #pragma unroll
    for (int i = 0; i < 4; ++i) {
      int r = rbase + mt * 16 + i;
      if (r < cnt) {
        int t = tokd[r];
        float gv = gated[r];
        float* orow = out + (size_t)t * DM + cbase;
        #pragma unroll
        for (int nt = 0; nt < 4; ++nt)
          atomicAdd(orow + nt * 16, acc[mt][nt][i] * gv);  // rows unique per expert -> contention-free
      }
    }
  }
}

extern "C" void kernel_launch(void* const* d_in, const int* in_sizes, int n_in,
                              void* d_out, int out_size, void* d_ws, size_t ws_size,
                              hipStream_t stream) {
  (void)in_sizes; (void)n_in; (void)out_size; (void)ws_size;
  const float* x  = (const float*)d_in[0];
  const float* Wr = (const float*)d_in[1];
  const float* Wg = (const float*)d_in[2];
  const float* Wu = (const float*)d_in[3];
  const float* Wd = (const float*)d_in[4];
  float* out = (float*)d_out;

  char* ws = (char*)d_ws;
  int*   counts = (int*)(ws);                      // 4 ints
  int*   tok    = (int*)(ws + 1024);               // E*T ints
  float* gate   = (float*)(ws + 1024 + 4 * T_TOK * 4);
  u16*   Xe     = (u16*)(ws + 1024 + 2 * 4 * T_TOK * 4);   // [E][T][D] bf16, 33.5MB
  u16*   Wgt    = Xe  + (size_t)4 * T_TOK * DM;    // [F][D] bf16, per-expert reuse
  u16*   Wut    = Wgt + (size_t)FF * DM;
  u16*   Wdt    = Wut + (size_t)FF * DM;           // [D][F] bf16
  u16*   H      = Wdt + (size_t)DM * FF;           // [T][F] bf16, per-expert reuse
  const size_t DF = (size_t)DM * FF;

  hipMemsetAsync(out, 0, (size_t)T_TOK * DM * sizeof(float), stream);
  hipMemsetAsync(counts, 0, 4 * sizeof(int), stream);

  router_kernel<<<T_TOK / 4, 256, 0, stream>>>(x, Wr, counts, tok, gate);
  gather_kernel<<<4 * T_TOK, 256, 0, stream>>>(x, counts, tok, Xe);

  for (int e = 0; e < 4; ++e) {
    // Wg,Wu: [D,F] -> [F,D];  Wd: [F,D] -> [D,F]
    trans_cvt_kernel<<<dim3(FF / 64, DM / 64), 256, 0, stream>>>(Wg + e * DF, Wgt, DM, FF);
    trans_cvt_kernel<<<dim3(FF / 64, DM / 64), 256, 0, stream>>>(Wu + e * DF, Wut, DM, FF);
    trans_cvt_kernel<<<dim3(DM / 64, FF / 64), 256, 0, stream>>>(Wd + e * DF, Wdt, FF, DM);
    gemm12_kernel<<<dim3(FF / 128, T_TOK / 128), 256, 0, stream>>>(
        Xe + (size_t)e * T_TOK * DM, Wgt, Wut, H, counts + e);
    gemm3_kernel<<<dim3(DM / 128, T_TOK / 128), 256, 0, stream>>>(
        H, Wdt, out, counts + e, tok + e * T_TOK, gate + e * T_TOK);
  }
}

// Round 2
// 1334.333 us; speedup vs baseline: 1.2475x; 1.2475x over previous
//
#include <hip/hip_runtime.h>
#include <stdint.h>

// MoE top-2 routed SwiGLU. B=2,S=1024 -> T=2048 tokens, D=2048, F=8192, E=4, K=2.
// R2: merged launches — 1 transpose (all 12 jobs), 1 gemm12 (all experts),
// 1 gemm3 (all experts, K-split z=2). GEMM cores identical to verified R1.
// ws budget: poison fill showed ws_size = 1 GiB; we use ~570 MB.

#define T_TOK 2048
#define DM    2048
#define FF    8192
#define DF    ((size_t)DM * FF)

typedef unsigned short u16;
typedef short short8 __attribute__((ext_vector_type(8)));
typedef float f32x4  __attribute__((ext_vector_type(4)));

#define GLL16(g, l) __builtin_amdgcn_global_load_lds( \
    (const __attribute__((address_space(1))) void*)(g), \
    (__attribute__((address_space(3))) void*)(l), 16, 0, 0)

__device__ __forceinline__ u16 f2bf(float f) {
  uint32_t x = __float_as_uint(f);
  x += 0x7fffu + ((x >> 16) & 1u);
  return (u16)(x >> 16);
}

// ---------------- router: probs + top2 + slot assignment ----------------
__global__ __launch_bounds__(256) void router_kernel(
    const float* __restrict__ x, const float* __restrict__ Wr,
    int* __restrict__ counts, int* __restrict__ tok, float* __restrict__ gate)
{
  int t = blockIdx.x * 4 + (threadIdx.x >> 6);   // one wave per token
  int l = threadIdx.x & 63;
  const float* xr = x + (size_t)t * DM;
  const float4* wr4 = (const float4*)Wr;         // Wr row d = 4 consecutive floats
  float a0 = 0.f, a1 = 0.f, a2 = 0.f, a3 = 0.f;
  for (int d = l; d < DM; d += 64) {
    float xv = xr[d];
    float4 w = wr4[d];
    a0 += xv * w.x; a1 += xv * w.y; a2 += xv * w.z; a3 += xv * w.w;
  }
  #pragma unroll
  for (int off = 32; off > 0; off >>= 1) {
    a0 += __shfl_down(a0, off);
    a1 += __shfl_down(a1, off);
    a2 += __shfl_down(a2, off);
    a3 += __shfl_down(a3, off);
  }
  if (l == 0) {
    float lg[4] = {a0, a1, a2, a3};
    float m = fmaxf(fmaxf(lg[0], lg[1]), fmaxf(lg[2], lg[3]));
    float p[4], s = 0.f;
    #pragma unroll
    for (int e = 0; e < 4; ++e) { p[e] = __expf(lg[e] - m); s += p[e]; }
    #pragma unroll
    for (int e = 0; e < 4; ++e) p[e] /= s;
    int i0 = 0;
    #pragma unroll
    for (int e = 1; e < 4; ++e) if (p[e] > p[i0]) i0 = e;      // ties -> lower idx, matches lax.top_k
    int i1 = (i0 == 0) ? 1 : 0;
    #pragma unroll
    for (int e = 0; e < 4; ++e) if (e != i0 && p[e] > p[i1]) i1 = e;
    int s0 = atomicAdd(&counts[i0], 1);
    tok[i0 * T_TOK + s0] = t; gate[i0 * T_TOK + s0] = p[i0];
    int s1 = atomicAdd(&counts[i1], 1);
    tok[i1 * T_TOK + s1] = t; gate[i1 * T_TOK + s1] = p[i1];
  }
}

// ---------------- gather token rows -> per-expert contiguous bf16 A ----------------
__global__ __launch_bounds__(256) void gather_kernel(
    const float* __restrict__ x, const int* __restrict__ counts,
    const int* __restrict__ tok, u16* __restrict__ Xe)
{
  int e = blockIdx.x >> 11;
  int slot = blockIdx.x & (T_TOK - 1);
  if (slot >= counts[e]) return;
  int t = tok[e * T_TOK + slot];
  const float4* src = (const float4*)(x + (size_t)t * DM);
  u16* dst = Xe + ((size_t)e * T_TOK + slot) * DM;
  int i = threadIdx.x;                           // 256 thr x 8 elems = 2048
  float4 a = src[i * 2], b = src[i * 2 + 1];
  union { u16 h[8]; uint4 q; } v;
  v.h[0] = f2bf(a.x); v.h[1] = f2bf(a.y); v.h[2] = f2bf(a.z); v.h[3] = f2bf(a.w);
  v.h[4] = f2bf(b.x); v.h[5] = f2bf(b.y); v.h[6] = f2bf(b.z); v.h[7] = f2bf(b.w);
  *(uint4*)(dst + i * 8) = v.q;
}

// ---------------- transpose + fp32->bf16 convert, ALL 12 jobs in one launch ----------------
// jobs 0-3: Wg[e] [D,F]->[F,D]; 4-7: Wu[e]; 8-11: Wd[e] [F,D]->[D,F]
__global__ __launch_bounds__(256) void trans_cvt_all(
    const float* __restrict__ Wg, const float* __restrict__ Wu, const float* __restrict__ Wd,
    u16* __restrict__ Wgt, u16* __restrict__ Wut, u16* __restrict__ Wdt)
{
  int j = blockIdx.y;
  const float* src; u16* dst; int R, C, clog;
  if (j < 4)      { src = Wg + (size_t)j * DF;       dst = Wgt + (size_t)j * DF;       R = DM; C = FF; clog = 7; }
  else if (j < 8) { src = Wu + (size_t)(j - 4) * DF; dst = Wut + (size_t)(j - 4) * DF; R = DM; C = FF; clog = 7; }
  else            { src = Wd + (size_t)(j - 8) * DF; dst = Wdt + (size_t)(j - 8) * DF; R = FF; C = DM; clog = 5; }
  int bx = blockIdx.x;
  int c0 = (bx & ((1 << clog) - 1)) * 64;
  int r0 = (bx >> clog) * 64;

  __shared__ float tile[64][65];                 // +1 pad: conflict-free transpose
  int tid = threadIdx.x;
  int tc = tid & 63, tr = tid >> 6;
  #pragma unroll
  for (int i = 0; i < 16; ++i) {
    int row = i * 4 + tr;
    tile[row][tc] = src[(size_t)(r0 + row) * C + c0 + tc];
  }
  __syncthreads();
  int wr = tid & 15, rr = tid >> 4;
  #pragma unroll
  for (int i = 0; i < 4; ++i) {
    int row = i * 16 + rr;
    ushort4 v;
    v.x = f2bf(tile[wr * 4 + 0][row]);
    v.y = f2bf(tile[wr * 4 + 1][row]);
    v.z = f2bf(tile[wr * 4 + 2][row]);
    v.w = f2bf(tile[wr * 4 + 3][row]);
    *(ushort4*)&dst[(size_t)(c0 + row) * R + r0 + wr * 4] = v;
  }
}

// ---------------- GEMM12 (all experts): H = silu(A@WgT') * (A@WuT') ----------------
// grid: x = FF/128 col-blocks, y = e*16 + row-block
__global__ __launch_bounds__(256, 2) void gemm12_kernel(
    const u16* __restrict__ XeB, const u16* __restrict__ WgtB, const u16* __restrict__ WutB,
    u16* __restrict__ HB, const int* __restrict__ counts)
{
  const int e  = blockIdx.y >> 4;
  const int rb = blockIdx.y & 15;
  const int cnt = counts[e];
  if (rb * 128 >= cnt) return;
  const u16* A  = XeB + (size_t)e * T_TOK * DM;
  const u16* Bg = WgtB + (size_t)e * DF;
  const u16* Bu = WutB + (size_t)e * DF;
  u16* H = HB + (size_t)e * T_TOK * FF;

  __shared__ __align__(16) u16 As[128 * 64];
  __shared__ __align__(16) u16 Bgs[128 * 64];
  __shared__ __align__(16) u16 Bus[128 * 64];
  const int tid = threadIdx.x, l = tid & 63, w = tid >> 6;
  const int wm = w & 1, wn = w >> 1;
  // staging: XOR swizzle on the GLOBAL side (LDS dst is wave-uniform base + lane*16)
  const int cg = (l & 7) ^ (l >> 3);
  const u16* ap[4]; const u16* bgp[4]; const u16* bup[4];
  const u16* la[4]; const u16* lbg[4]; const u16* lbu[4];
  #pragma unroll
  for (int j = 0; j < 4; ++j) {
    int r0 = (w * 4 + j) * 8;
    int row = r0 + (l >> 3);
    ap[j]  = A  + (size_t)(rb * 128 + row) * DM + cg * 8;
    bgp[j] = Bg + (size_t)(blockIdx.x * 128 + row) * DM + cg * 8;
    bup[j] = Bu + (size_t)(blockIdx.x * 128 + row) * DM + cg * 8;
    la[j]  = As  + r0 * 64;
    lbg[j] = Bgs + r0 * 64;
    lbu[j] = Bus + r0 * 64;
  }
  int fm[4], fn[4];
  #pragma unroll
  for (int i = 0; i < 4; ++i) {
    fm[i] = (wm * 64 + i * 16 + (l & 15)) * 64;
    fn[i] = (wn * 64 + i * 16 + (l & 15)) * 64;
  }
  f32x4 accg[4][4] = {};
  f32x4 accu[4][4] = {};
  for (int kt = 0; kt < DM / 64; ++kt) {
    #pragma unroll
    for (int j = 0; j < 4; ++j) {
      GLL16(ap[j]  + kt * 64, la[j]);
      GLL16(bgp[j] + kt * 64, lbg[j]);
      GLL16(bup[j] + kt * 64, lbu[j]);
    }
    __syncthreads();
    #pragma unroll
    for (int kk = 0; kk < 2; ++kk) {
      const int c2 = ((kk * 4 + (l >> 4)) ^ (l & 7)) * 8;
      short8 af[4], bgf[4], buf_[4];
      #pragma unroll
      for (int i = 0; i < 4; ++i) af[i]   = *(const short8*)&As[fm[i] + c2];
      #pragma unroll
      for (int i = 0; i < 4; ++i) bgf[i]  = *(const short8*)&Bgs[fn[i] + c2];
      #pragma unroll
      for (int i = 0; i < 4; ++i) buf_[i] = *(const short8*)&Bus[fn[i] + c2];
      #pragma unroll
      for (int mt = 0; mt < 4; ++mt)
        #pragma unroll
        for (int nt = 0; nt < 4; ++nt) {
          accg[mt][nt] = __builtin_amdgcn_mfma_f32_16x16x32_bf16(af[mt], bgf[nt],  accg[mt][nt], 0, 0, 0);
          accu[mt][nt] = __builtin_amdgcn_mfma_f32_16x16x32_bf16(af[mt], buf_[nt], accu[mt][nt], 0, 0, 0);
        }
    }
    __syncthreads();
  }
  // epilogue: C/D layout col=lane&15, row=(lane>>4)*4+reg (m89-verified)
  const int rbase = rb * 128 + wm * 64 + ((l >> 4) << 2);
  const int cbase = blockIdx.x * 128 + wn * 64 + (l & 15);
  #pragma unroll
  for (int mt = 0; mt < 4; ++mt) {
    #pragma unroll
    for (int i = 0; i < 4; ++i) {
      int r = rbase + mt * 16 + i;
      u16* hrow = H + (size_t)r * FF + cbase;
      #pragma unroll
      for (int nt = 0; nt < 4; ++nt) {
        float g = accg[mt][nt][i], u = accu[mt][nt][i];
        float h = (g / (1.f + __expf(-g))) * u;   // silu(g)*u
        hrow[nt * 16] = f2bf(h);
      }
    }
  }
}

// ---------------- GEMM3 (all experts, K-split): out[tok[r]] += gate[r]*(H@WdT') ----------------
// grid: x = DM/128 col-blocks, y = e*16 + row-block, z = K-half (0/1)
__global__ __launch_bounds__(256, 2) void gemm3_kernel(
    const u16* __restrict__ HB, const u16* __restrict__ WdtB,
    float* __restrict__ out, const int* __restrict__ counts,
    const int* __restrict__ tokB, const float* __restrict__ gateB)
{
  const int e  = blockIdx.y >> 4;
  const int rb = blockIdx.y & 15;
  const int cnt = counts[e];
  if (rb * 128 >= cnt) return;
  const u16* A = HB + (size_t)e * T_TOK * FF;
  const u16* B = WdtB + (size_t)e * DF;
  const int* tokd = tokB + e * T_TOK;
  const float* gated = gateB + e * T_TOK;
  const int kt0 = blockIdx.z * 64, kt1 = kt0 + 64;   // each handles K/2 = 4096

  __shared__ __align__(16) u16 As[128 * 64];
  __shared__ __align__(16) u16 Bs[128 * 64];
  const int tid = threadIdx.x, l = tid & 63, w = tid >> 6;
  const int wm = w & 1, wn = w >> 1;
  const int cg = (l & 7) ^ (l >> 3);
  const u16* ap[4]; const u16* bp[4]; const u16* la[4]; const u16* lb[4];
  #pragma unroll
  for (int j = 0; j < 4; ++j) {
    int r0 = (w * 4 + j) * 8;
    int row = r0 + (l >> 3);
    ap[j] = A + (size_t)(rb * 128 + row) * FF + cg * 8;
    bp[j] = B + (size_t)(blockIdx.x * 128 + row) * FF + cg * 8;
    la[j] = As + r0 * 64;
    lb[j] = Bs + r0 * 64;
  }
  int fm[4], fn[4];
  #pragma unroll
  for (int i = 0; i < 4; ++i) {
    fm[i] = (wm * 64 + i * 16 + (l & 15)) * 64;
    fn[i] = (wn * 64 + i * 16 + (l & 15)) * 64;
  }
  f32x4 acc[4][4] = {};
  for (int kt = kt0; kt < kt1; ++kt) {
    #pragma unroll
    for (int j = 0; j < 4; ++j) {
      GLL16(ap[j] + kt * 64, la[j]);
      GLL16(bp[j] + kt * 64, lb[j]);
    }
    __syncthreads();
    #pragma unroll
    for (int kk = 0; kk < 2; ++kk) {
      const int c2 = ((kk * 4 + (l >> 4)) ^ (l & 7)) * 8;
      short8 af[4], bf[4];
      #pragma unroll
      for (int i = 0; i < 4; ++i) af[i] = *(const short8*)&As[fm[i] + c2];
      #pragma unroll
      for (int i = 0; i < 4; ++i) bf[i] = *(const short8*)&Bs[fn[i] + c2];
      #pragma unroll
      for (int mt = 0; mt < 4; ++mt)
        #pragma unroll
        for (int nt = 0; nt < 4; ++nt)
          acc[mt][nt] = __builtin_amdgcn_mfma_f32_16x16x32_bf16(af[mt], bf[nt], acc[mt][nt], 0, 0, 0);
    }
    __syncthreads();
  }
  const int rbase = rb * 128 + wm * 64 + ((l >> 4) << 2);
  const int cbase = blockIdx.x * 128 + wn * 64 + (l & 15);
  #pragma unroll
  for (int mt = 0; mt < 4; ++mt) {
    #pragma unroll
    for (int i = 0; i < 4; ++i) {
      int r = rbase + mt * 16 + i;
      if (r < cnt) {
        int t = tokd[r];
        float gv = gated[r];
        float* orow = out + (size_t)t * DM + cbase;
        #pragma unroll
        for (int nt = 0; nt < 4; ++nt)
          atomicAdd(orow + nt * 16, acc[mt][nt][i] * gv);  // distinct addrs; cross-block races resolved by atomic
      }
    }
  }
}

extern "C" void kernel_launch(void* const* d_in, const int* in_sizes, int n_in,
                              void* d_out, int out_size, void* d_ws, size_t ws_size,
                              hipStream_t stream) {
  (void)in_sizes; (void)n_in; (void)out_size; (void)ws_size;
  const float* x  = (const float*)d_in[0];
  const float* Wr = (const float*)d_in[1];
  const float* Wg = (const float*)d_in[2];
  const float* Wu = (const float*)d_in[3];
  const float* Wd = (const float*)d_in[4];
  float* out = (float*)d_out;

  char* ws = (char*)d_ws;
  int*   counts = (int*)(ws);                            // 4 ints
  int*   tok    = (int*)(ws + 1024);                     // E*T ints
  float* gate   = (float*)(ws + 1024 + 4 * T_TOK * 4);
  u16*   Xe     = (u16*)(ws + 1024 + 2 * 4 * T_TOK * 4); // [E][T][D]  33.5 MB
  u16*   Wgt    = Xe  + (size_t)4 * T_TOK * DM;          // [E][F][D] 134 MB
  u16*   Wut    = Wgt + 4 * DF;                          // [E][F][D] 134 MB
  u16*   Wdt    = Wut + 4 * DF;                          // [E][D][F] 134 MB
  u16*   H      = Wdt + 4 * DF;                          // [E][T][F] 134 MB  (total ~570 MB < 1 GiB ws)

  hipMemsetAsync(out, 0, (size_t)T_TOK * DM * sizeof(float), stream);
  hipMemsetAsync(counts, 0, 4 * sizeof(int), stream);

  router_kernel<<<T_TOK / 4, 256, 0, stream>>>(x, Wr, counts, tok, gate);
  gather_kernel<<<4 * T_TOK, 256, 0, stream>>>(x, counts, tok, Xe);
  trans_cvt_all<<<dim3(4096, 12), 256, 0, stream>>>(Wg, Wu, Wd, Wgt, Wut, Wdt);
  gemm12_kernel<<<dim3(FF / 128, 64), 256, 0, stream>>>(Xe, Wgt, Wut, H, counts);
  gemm3_kernel<<<dim3(DM / 128, 64, 2), 256, 0, stream>>>(H, Wdt, out, counts, tok, gate);
}